// Round 4
// baseline (1581.971 us; speedup 1.0000x reference)
//
#include <hip/hip_runtime.h>
#include <hip/hip_bf16.h>
#include <cstdint>

#define N_NODES 50000
#define N_EDGES 500000
#define HID 128
#define NLAYERS 4
#define NGRAPHS 64

typedef float f32x4 __attribute__((ext_vector_type(4)));
typedef __bf16 bf16x8 __attribute__((ext_vector_type(8)));

// ---- all scratch lives in device globals (allocated at module load; d_ws unused) ----
__device__ float          g_h[(size_t)N_NODES * HID];
__device__ unsigned short g_hb[(size_t)N_NODES * HID];
__device__ float          g_aggr[(size_t)N_NODES * HID];
__device__ float          g_dists[N_EDGES];
__device__ int            g_dsts[N_EDGES];
__device__ int            g_srcs[N_EDGES];
__device__ int            g_cnt[N_NODES];
__device__ int            g_cursor[N_NODES];
__device__ int            g_bsum[1024];
__device__ unsigned short g_mw1p[NLAYERS * 8 * 8 * 64 * 8];   // msg W1 packed
__device__ unsigned short g_mw2p[NLAYERS * 4 * 8 * 64 * 8];   // msg W2 packed
__device__ unsigned short g_uw1p[NLAYERS * 8 * 8 * 64 * 8];   // upd W1 packed
__device__ unsigned short g_uw2p[NLAYERS * 4 * 8 * 64 * 8];   // upd W2 packed
__device__ float          g_pooled[NGRAPHS * HID];

__device__ __forceinline__ unsigned short f2bf(float f) {
    uint32_t u = __builtin_bit_cast(uint32_t, f);
    uint32_t r = (u + 0x7fffu + ((u >> 16) & 1u)) >> 16;
    return (unsigned short)r;
}

// ---------------- clear kernels (replace hipMemsetAsync on symbol memory) ----------------
__global__ void clear_cnt_k() {
    int i = blockIdx.x * 256 + threadIdx.x;
    if (i < N_NODES) g_cnt[i] = 0;
}
__global__ void clear_aggr_k() {   // grid = N_NODES*HID/256 = 25000 exactly
    size_t i = (size_t)blockIdx.x * 256 + threadIdx.x;
    g_aggr[i] = 0.f;
}

// ---------------- weight pre-pack into MFMA B-fragment layout ----------------
// B-frag for 16x16x32: lane l holds B[k = ks*32 + (l>>4)*8 + j][n = nt*16 + (l&15)], j=0..7
// which = 0: g_mw1p, 1: g_mw2p, 2: g_uw1p, 3: g_uw2p
__global__ void pack_w(const float* __restrict__ src, int which,
                       int ksteps, int layer_stride) {
    int lane = threadIdx.x;                 // 64
    int bid = blockIdx.x;
    int nt = bid & 7;
    int ks = (bid >> 3) % ksteps;
    int layer = bid / (8 * ksteps);
    unsigned short* dst = (which == 0) ? g_mw1p : (which == 1) ? g_mw2p
                        : (which == 2) ? g_uw1p : g_uw2p;
    const float* s = src + (size_t)layer * layer_stride;
    int kbase = ks * 32 + (lane >> 4) * 8;
    int n = nt * 16 + (lane & 15);
    unsigned short tmp[8];
#pragma unroll
    for (int j = 0; j < 8; ++j) tmp[j] = f2bf(s[(size_t)(kbase + j) * HID + n]);
    uint32_t w0 = tmp[0] | ((uint32_t)tmp[1] << 16);
    uint32_t w1 = tmp[2] | ((uint32_t)tmp[3] << 16);
    uint32_t w2 = tmp[4] | ((uint32_t)tmp[5] << 16);
    uint32_t w3 = tmp[6] | ((uint32_t)tmp[7] << 16);
    size_t o = (((size_t)(layer * ksteps + ks) * 8 + nt) * 64 + lane) * 8;
    *(uint4*)&dst[o] = make_uint4(w0, w1, w2, w3);
}

// ---------------- node encoder: h = x @ enc_w + enc_b ----------------
__global__ void encode_k(const float* __restrict__ x, const float* __restrict__ w,
                         const float* __restrict__ b) {
    __shared__ float xl[2][15];
    int t = threadIdx.x;
    int half = t >> 7;
    int node = blockIdx.x * 2 + half;
    int c = t & 127;
    if (c < 15) xl[half][c] = x[(size_t)node * 15 + c];
    __syncthreads();
    float acc = b[c];
#pragma unroll
    for (int k = 0; k < 15; ++k) acc += xl[half][k] * w[k * HID + c];
    g_h[(size_t)node * HID + c] = acc;
    g_hb[(size_t)node * HID + c] = f2bf(acc);
}

// ---------------- histogram of dst ----------------
__global__ void hist_k(const int* __restrict__ ei) {
    int e = blockIdx.x * 256 + threadIdx.x;
    if (e < N_EDGES) atomicAdd(&g_cnt[ei[N_EDGES + e]], 1);
}

// ---------------- scan (3 kernels) ----------------
__global__ void scanA_k() {
    __shared__ int s[512];
    int t = threadIdx.x;
    int i = blockIdx.x * 512 + t;
    s[t] = (i < N_NODES) ? g_cnt[i] : 0;
    __syncthreads();
    for (int d = 256; d > 0; d >>= 1) {
        if (t < d) s[t] += s[t + d];
        __syncthreads();
    }
    if (t == 0) g_bsum[blockIdx.x] = s[0];
}

__global__ void scanB_k(int nb) {
    if (threadIdx.x == 0) {
        int acc = 0;
        for (int i = 0; i < nb; ++i) { int v = g_bsum[i]; g_bsum[i] = acc; acc += v; }
    }
}

__global__ void scanC_k() {
    __shared__ int s[512];
    int t = threadIdx.x;
    int i = blockIdx.x * 512 + t;
    int v = (i < N_NODES) ? g_cnt[i] : 0;
    s[t] = v;
    __syncthreads();
    for (int d = 1; d < 512; d <<= 1) {
        int add = (t >= d) ? s[t - d] : 0;
        __syncthreads();
        s[t] += add;
        __syncthreads();
    }
    if (i < N_NODES) g_cursor[i] = g_bsum[blockIdx.x] + s[t] - v;
}

// ---------------- scatter into dst-sorted order (+ fused dist computation) ----------------
__global__ void scatter_k(const int* __restrict__ ei, const float* __restrict__ pos) {
    int e = blockIdx.x * 256 + threadIdx.x;
    if (e >= N_EDGES) return;
    int s = ei[e];
    int d = ei[N_EDGES + e];
    float dx = pos[d * 3 + 0] - pos[s * 3 + 0];
    float dy = pos[d * 3 + 1] - pos[s * 3 + 1];
    float dz = pos[d * 3 + 2] - pos[s * 3 + 2];
    int p = atomicAdd(&g_cursor[d], 1);
    g_dsts[p] = d;
    g_srcs[p] = s;
    g_dists[p] = sqrtf(dx * dx + dy * dy + dz * dz);
}

// ---------------- fused edge message MLP + segmented scatter-add ----------------
// tile = 64 sorted edges; A = [h[dst] | h[src]] (64x256 bf16, XOR-swizzled LDS)
// GEMM1 (K=256) + dist rank-1 + bias + relu -> Hbuf ; GEMM2 (K=128) + b2 -> Obuf
// then per-column segmented reduce over sorted dst + atomicAdd into aggr.
__global__ __launch_bounds__(256, 2)
void edge_msg_k(const float* __restrict__ w1last, const float* __restrict__ b1,
                const float* __restrict__ b2, int L) {
    __shared__ unsigned short Abuf[64 * 256];   // 32KB; aliased as Obuf (f32 64x128) later
    __shared__ unsigned short Hbuf[64 * 128];   // 16KB
    __shared__ int dstb[64];
    __shared__ float distb[64];
    float* Obuf = (float*)Abuf;
    const unsigned short* w1p = g_mw1p + (size_t)L * 8 * 8 * 64 * 8;
    const unsigned short* w2p = g_mw2p + (size_t)L * 4 * 8 * 64 * 8;

    int t = threadIdx.x;
    int tile0 = blockIdx.x * 64;

    { // stage A (gather, f32->bf16 already done in g_hb), swizzle slot ^= row&7
        int r = t >> 2, p = t & 3;
        int sidx = tile0 + r;
        bool valid = sidx < N_EDGES;
        int nd = 0, ns = 0;
        if (valid) { nd = g_dsts[sidx]; ns = g_srcs[sidx]; }
        if (p == 0) {
            dstb[r] = valid ? nd : 0x7fffffff;
            distb[r] = valid ? g_dists[sidx] : 0.f;
        }
#pragma unroll
        for (int q = 0; q < 8; ++q) {
            int slot = p * 8 + q;               // 0..31 (16B units), 0..15=dst row, 16..31=src row
            uint4 v = make_uint4(0, 0, 0, 0);
            if (valid) {
                int node = (slot < 16) ? nd : ns;
                v = *(const uint4*)&g_hb[(size_t)node * HID + (slot & 15) * 8];
            }
            int ws = slot ^ (r & 7);
            *(uint4*)&Abuf[r * 256 + ws * 8] = v;
        }
    }
    __syncthreads();

    int wave = t >> 6, lane = t & 63;
    int arow = lane & 15, kgrp = lane >> 4;
    int row16 = wave * 16 + arow;

    // GEMM1: K=256, 8 ksteps
    f32x4 acc[8];
#pragma unroll
    for (int i = 0; i < 8; ++i) acc[i] = (f32x4){0.f, 0.f, 0.f, 0.f};
#pragma unroll
    for (int ks = 0; ks < 8; ++ks) {
        int slot = ks * 4 + kgrp;
        bf16x8 a = *(const bf16x8*)&Abuf[row16 * 256 + (slot ^ (arow & 7)) * 8];
#pragma unroll
        for (int nt = 0; nt < 8; ++nt) {
            bf16x8 b = *(const bf16x8*)&w1p[(size_t)((ks * 8 + nt) * 64 + lane) * 8];
            acc[nt] = __builtin_amdgcn_mfma_f32_16x16x32_bf16(a, b, acc[nt], 0, 0, 0);
        }
    }
    // epilogue 1: + dist*w1last + b1, relu, -> Hbuf (bf16, swizzled)
#pragma unroll
    for (int nt = 0; nt < 8; ++nt) {
        int col = nt * 16 + arow;
        float wl = w1last[col], bb = b1[col];
#pragma unroll
        for (int q = 0; q < 4; ++q) {
            int row = wave * 16 + kgrp * 4 + q;
            float hv = acc[nt][q] + distb[row] * wl + bb;
            hv = fmaxf(hv, 0.f);
            int slotH = col >> 3;
            Hbuf[row * 128 + ((slotH ^ (row & 7)) << 3) + (col & 7)] = f2bf(hv);
        }
    }
    __syncthreads();

    // GEMM2: K=128, 4 ksteps
    f32x4 acc2[8];
#pragma unroll
    for (int i = 0; i < 8; ++i) acc2[i] = (f32x4){0.f, 0.f, 0.f, 0.f};
#pragma unroll
    for (int ks = 0; ks < 4; ++ks) {
        int slot = ks * 4 + kgrp;
        bf16x8 a = *(const bf16x8*)&Hbuf[row16 * 128 + (slot ^ (arow & 7)) * 8];
#pragma unroll
        for (int nt = 0; nt < 8; ++nt) {
            bf16x8 b = *(const bf16x8*)&w2p[(size_t)((ks * 8 + nt) * 64 + lane) * 8];
            acc2[nt] = __builtin_amdgcn_mfma_f32_16x16x32_bf16(a, b, acc2[nt], 0, 0, 0);
        }
    }
    // epilogue 2: + b2 -> Obuf (f32). Safe to alias Abuf: all waves are past GEMM1
    // (barrier after Hbuf writes) and GEMM2 reads only Hbuf.
#pragma unroll
    for (int nt = 0; nt < 8; ++nt) {
        int col = nt * 16 + arow;
        float bb = b2[col];
#pragma unroll
        for (int q = 0; q < 4; ++q) {
            int row = wave * 16 + kgrp * 4 + q;
            Obuf[row * 128 + col] = acc2[nt][q] + bb;
        }
    }
    __syncthreads();

    // segmented reduce over sorted dst, then one atomicAdd per (segment, col)
    {
        int c = t & 127, half = t >> 7;
        int rbeg = half * 32, rend = rbeg + 32;
        for (int r = rbeg; r < rend; ++r) {
            int d = dstb[r];
            if (d == 0x7fffffff) break;             // padding rows (end of last tile)
            if (r > 0 && dstb[r - 1] == d) continue; // not a segment head
            float s = 0.f;
            int rr = r;
            while (rr < 64 && dstb[rr] == d) { s += Obuf[rr * 128 + c]; ++rr; }
            atomicAdd(&g_aggr[(size_t)d * HID + c], s);
        }
    }
}

// ---------------- fused node update MLP + LayerNorm + relu + residual ----------------
__global__ __launch_bounds__(256, 2)
void node_upd_k(const float* __restrict__ b1, const float* __restrict__ b2,
                const float* __restrict__ lng, const float* __restrict__ lnb,
                int L, int first_layer) {
    __shared__ unsigned short Abuf[64 * 256];
    __shared__ unsigned short Hbuf[64 * 128];
    const unsigned short* w1p = g_uw1p + (size_t)L * 8 * 8 * 64 * 8;
    const unsigned short* w2p = g_uw2p + (size_t)L * 4 * 8 * 64 * 8;
    int t = threadIdx.x;
    int tile0 = blockIdx.x * 64;

    { // stage A = [h | aggr] -> bf16, swizzled
        int r = t >> 2, p = t & 3;
        int n = tile0 + r;
        bool valid = n < N_NODES;
#pragma unroll
        for (int q = 0; q < 8; ++q) {
            int slot = p * 8 + q;
            unsigned short tmp[8];
            if (valid) {
                const float* sp = (slot < 16) ? &g_h[(size_t)n * HID + (slot & 15) * 8]
                                              : &g_aggr[(size_t)n * HID + (slot & 15) * 8];
#pragma unroll
                for (int j = 0; j < 8; ++j) tmp[j] = f2bf(sp[j]);
            } else {
#pragma unroll
                for (int j = 0; j < 8; ++j) tmp[j] = 0;
            }
            uint32_t u0 = tmp[0] | ((uint32_t)tmp[1] << 16);
            uint32_t u1 = tmp[2] | ((uint32_t)tmp[3] << 16);
            uint32_t u2 = tmp[4] | ((uint32_t)tmp[5] << 16);
            uint32_t u3 = tmp[6] | ((uint32_t)tmp[7] << 16);
            int ws = slot ^ (r & 7);
            *(uint4*)&Abuf[r * 256 + ws * 8] = make_uint4(u0, u1, u2, u3);
        }
    }
    __syncthreads();

    int wave = t >> 6, lane = t & 63;
    int arow = lane & 15, kgrp = lane >> 4;
    int row16 = wave * 16 + arow;

    f32x4 acc[8];
#pragma unroll
    for (int i = 0; i < 8; ++i) acc[i] = (f32x4){0.f, 0.f, 0.f, 0.f};
#pragma unroll
    for (int ks = 0; ks < 8; ++ks) {
        int slot = ks * 4 + kgrp;
        bf16x8 a = *(const bf16x8*)&Abuf[row16 * 256 + (slot ^ (arow & 7)) * 8];
#pragma unroll
        for (int nt = 0; nt < 8; ++nt) {
            bf16x8 b = *(const bf16x8*)&w1p[(size_t)((ks * 8 + nt) * 64 + lane) * 8];
            acc[nt] = __builtin_amdgcn_mfma_f32_16x16x32_bf16(a, b, acc[nt], 0, 0, 0);
        }
    }
#pragma unroll
    for (int nt = 0; nt < 8; ++nt) {
        int col = nt * 16 + arow;
        float bb = b1[col];
#pragma unroll
        for (int q = 0; q < 4; ++q) {
            int row = wave * 16 + kgrp * 4 + q;
            float hv = fmaxf(acc[nt][q] + bb, 0.f);
            int slotH = col >> 3;
            Hbuf[row * 128 + ((slotH ^ (row & 7)) << 3) + (col & 7)] = f2bf(hv);
        }
    }
    __syncthreads();

    f32x4 acc2[8];
#pragma unroll
    for (int i = 0; i < 8; ++i) acc2[i] = (f32x4){0.f, 0.f, 0.f, 0.f};
#pragma unroll
    for (int ks = 0; ks < 4; ++ks) {
        int slot = ks * 4 + kgrp;
        bf16x8 a = *(const bf16x8*)&Hbuf[row16 * 128 + (slot ^ (arow & 7)) * 8];
#pragma unroll
        for (int nt = 0; nt < 8; ++nt) {
            bf16x8 b = *(const bf16x8*)&w2p[(size_t)((ks * 8 + nt) * 64 + lane) * 8];
            acc2[nt] = __builtin_amdgcn_mfma_f32_16x16x32_bf16(a, b, acc2[nt], 0, 0, 0);
        }
    }

    // LayerNorm over 128 features (rows live within a 16-lane group), relu, residual
    float sum[4] = {0, 0, 0, 0}, ss[4] = {0, 0, 0, 0};
#pragma unroll
    for (int nt = 0; nt < 8; ++nt) {
        int col = nt * 16 + arow;
        float bb = b2[col];
#pragma unroll
        for (int q = 0; q < 4; ++q) {
            float v = acc2[nt][q] + bb;
            acc2[nt][q] = v;
            sum[q] += v;
            ss[q] += v * v;
        }
    }
#pragma unroll
    for (int m = 1; m < 16; m <<= 1) {
#pragma unroll
        for (int q = 0; q < 4; ++q) {
            sum[q] += __shfl_xor(sum[q], m);
            ss[q] += __shfl_xor(ss[q], m);
        }
    }
    float mean[4], rstd[4];
#pragma unroll
    for (int q = 0; q < 4; ++q) {
        mean[q] = sum[q] * (1.f / HID);
        float var = ss[q] * (1.f / HID) - mean[q] * mean[q];
        rstd[q] = rsqrtf(var + 1e-5f);
    }
#pragma unroll
    for (int nt = 0; nt < 8; ++nt) {
        int col = nt * 16 + arow;
        float g = lng[col], bb = lnb[col];
#pragma unroll
        for (int q = 0; q < 4; ++q) {
            int row = tile0 + wave * 16 + kgrp * 4 + q;
            if (row < N_NODES) {
                float u = (acc2[nt][q] - mean[q]) * rstd[q] * g + bb;
                u = fmaxf(u, 0.f);
                float hn = first_layer ? u : (g_h[(size_t)row * HID + col] + u);
                g_h[(size_t)row * HID + col] = hn;
                g_hb[(size_t)row * HID + col] = f2bf(hn);
            }
        }
    }
}

// ---------------- global mean pool (batch is sorted) ----------------
__global__ void pool_k(const int* __restrict__ batch) {
    __shared__ int se[2];
    int g = blockIdx.x, t = threadIdx.x;
    if (t == 0) {
        int lo = 0, hi = N_NODES;
        while (lo < hi) { int m = (lo + hi) >> 1; if (batch[m] < g) lo = m + 1; else hi = m; }
        se[0] = lo;
        hi = N_NODES;
        while (lo < hi) { int m = (lo + hi) >> 1; if (batch[m] < g + 1) lo = m + 1; else hi = m; }
        se[1] = lo;
    }
    __syncthreads();
    int s = se[0], e = se[1];
    float acc = 0.f;
    for (int n = s; n < e; ++n) acc += g_h[(size_t)n * HID + t];
    g_pooled[g * HID + t] = acc / fmaxf((float)(e - s), 1.f);
}

// ---------------- readout MLP ----------------
__global__ void readout_k(const float* __restrict__ w1, const float* __restrict__ b1,
                          const float* __restrict__ w2, const float* __restrict__ b2,
                          const float* __restrict__ w3, const float* __restrict__ b3,
                          float* __restrict__ out) {
    __shared__ float p[128], o1[128], o2[64];
    int g = blockIdx.x, t = threadIdx.x;
    p[t] = g_pooled[g * HID + t];
    __syncthreads();
    float a = b1[t];
    for (int k = 0; k < 128; ++k) a += p[k] * w1[k * 128 + t];
    o1[t] = fmaxf(a, 0.f);
    __syncthreads();
    if (t < 64) {
        float a2 = b2[t];
        for (int k = 0; k < 128; ++k) a2 += o1[k] * w2[k * 64 + t];
        o2[t] = fmaxf(a2, 0.f);
    }
    __syncthreads();
    if (t == 0) {
        float a3 = b3[0];
        for (int k = 0; k < 64; ++k) a3 += o2[k] * w3[k];
        out[g] = a3;
    }
}

extern "C" void kernel_launch(void* const* d_in, const int* in_sizes, int n_in,
                              void* d_out, int out_size, void* d_ws, size_t ws_size,
                              hipStream_t stream) {
    const float* x     = (const float*)d_in[0];
    const int*   ei    = (const int*)d_in[1];
    const float* pos   = (const float*)d_in[3];
    const int*   batch = (const int*)d_in[4];
    const float* enc_w = (const float*)d_in[5];
    const float* enc_b = (const float*)d_in[6];
    const float* msg_w1 = (const float*)d_in[9];
    const float* msg_b1 = (const float*)d_in[10];
    const float* msg_w2 = (const float*)d_in[11];
    const float* msg_b2 = (const float*)d_in[12];
    const float* upd_w1 = (const float*)d_in[13];
    const float* upd_b1 = (const float*)d_in[14];
    const float* upd_w2 = (const float*)d_in[15];
    const float* upd_b2 = (const float*)d_in[16];
    const float* ln_g   = (const float*)d_in[17];
    const float* ln_b   = (const float*)d_in[18];
    const float* mw1 = (const float*)d_in[19];
    const float* mb1 = (const float*)d_in[20];
    const float* mw2 = (const float*)d_in[21];
    const float* mb2 = (const float*)d_in[22];
    const float* mw3 = (const float*)d_in[23];
    const float* mb3 = (const float*)d_in[24];
    float* out = (float*)d_out;
    (void)d_ws; (void)ws_size; (void)in_sizes; (void)n_in; (void)out_size;

    pack_w<<<NLAYERS * 8 * 8, 64, 0, stream>>>(msg_w1, 0, 8, 257 * HID);
    pack_w<<<NLAYERS * 4 * 8, 64, 0, stream>>>(msg_w2, 1, 4, HID * HID);
    pack_w<<<NLAYERS * 8 * 8, 64, 0, stream>>>(upd_w1, 2, 8, 256 * HID);
    pack_w<<<NLAYERS * 4 * 8, 64, 0, stream>>>(upd_w2, 3, 4, HID * HID);

    encode_k<<<N_NODES / 2, 256, 0, stream>>>(x, enc_w, enc_b);

    clear_cnt_k<<<(N_NODES + 255) / 256, 256, 0, stream>>>();
    hist_k<<<(N_EDGES + 255) / 256, 256, 0, stream>>>(ei);
    int nb = (N_NODES + 511) / 512;
    scanA_k<<<nb, 512, 0, stream>>>();
    scanB_k<<<1, 64, 0, stream>>>(nb);
    scanC_k<<<nb, 512, 0, stream>>>();
    scatter_k<<<(N_EDGES + 255) / 256, 256, 0, stream>>>(ei, pos);

    int etiles = (N_EDGES + 63) / 64;
    int ntiles = (N_NODES + 63) / 64;
    for (int L = 0; L < NLAYERS; ++L) {
        clear_aggr_k<<<(N_NODES * HID) / 256, 256, 0, stream>>>();
        edge_msg_k<<<etiles, 256, 0, stream>>>(
            msg_w1 + (size_t)L * 257 * HID + 256 * HID, msg_b1 + L * HID,
            msg_b2 + L * HID, L);
        node_upd_k<<<ntiles, 256, 0, stream>>>(
            upd_b1 + L * HID, upd_b2 + L * HID, ln_g + L * HID, ln_b + L * HID,
            L, L == 0 ? 1 : 0);
    }

    pool_k<<<NGRAPHS, 128, 0, stream>>>(batch);
    readout_k<<<NGRAPHS, 128, 0, stream>>>(mw1, mb1, mw2, mb2, mw3, mb3, out);
}